// Round 1
// baseline (3585.028 us; speedup 1.0000x reference)
//
#include <hip/hip_runtime.h>
#include <math.h>

#define B_   512
#define N_   193
#define D_   512
#define E_   2048
#define KTOK 96
#define H_   1024
#define M1   (B_ * KTOK)      // 49152
#define KGD  (KTOK * 4)       // 384

// ---------------- K0: zero BN stats ----------------
__global__ void zero_stats_kernel(double* stats) {
    int i = blockIdx.x * 256 + threadIdx.x;
    if (i < 2 * H_) stats[i] = 0.0;
}

// ---------------- K1: exact stable top-k (rank count) ----------------
__global__ void topk_kernel(const float* __restrict__ atten, int* __restrict__ idx) {
    __shared__ float s[N_];
    int b = blockIdx.x;
    const float* row = atten + (size_t)b * N_ * N_;   // atten[b, 0, :]
    for (int i = threadIdx.x; i < N_; i += blockDim.x)
        s[i] = (i == 0) ? -1.0f : row[i];
    __syncthreads();
    for (int i = threadIdx.x; i < N_; i += blockDim.x) {
        float v = s[i];
        int rank = 0;
        for (int j = 0; j < N_; ++j) {
            float u = s[j];
            rank += (u > v) || (u == v && j < i);
        }
        if (rank < KTOK) idx[b * KTOK + rank] = i;
    }
}

// ---------------- K2: gather + l2norm(X) + dyn-proj stage 1 (Y) ----------------
__global__ __launch_bounds__(256) void gather_kernel(
        const float* __restrict__ base, const int* __restrict__ idx,
        const float* __restrict__ W_dyn, const float* __restrict__ b_dyn,
        float* __restrict__ X, float* __restrict__ Y) {
    int rowid = blockIdx.x;                 // 0..49151 = b*96 + t
    int b = rowid / KTOK, t = rowid - b * KTOK;
    int tid = threadIdx.x;
    int tok = idx[rowid];
    const float* src = base + ((size_t)b * N_ + tok) * D_;
    float v0 = src[tid], v1 = src[tid + 256];

    float vals[5];
    vals[0] = v0 * v0 + v1 * v1;
#pragma unroll
    for (int r = 0; r < 4; ++r)
        vals[1 + r] = v0 * W_dyn[r * D_ + tid] + v1 * W_dyn[r * D_ + tid + 256];

    __shared__ float red[5][4];
    __shared__ float tot[5];
    int lane = tid & 63, wid = tid >> 6;
#pragma unroll
    for (int c = 0; c < 5; ++c) {
        float v = vals[c];
        for (int o = 32; o > 0; o >>= 1) v += __shfl_down(v, o, 64);
        if (lane == 0) red[c][wid] = v;
    }
    __syncthreads();
    if (tid < 5) tot[tid] = red[tid][0] + red[tid][1] + red[tid][2] + red[tid][3];
    __syncthreads();

    float norm = sqrtf(tot[0]) + 1e-8f;
    size_t xb = (size_t)rowid * D_;
    X[xb + tid]       = v0 / norm;
    X[xb + tid + 256] = v1 / norm;
    if (tid == 0) {
        int g = b >> 2;
        int n = (b & 3) * KTOK + t;
#pragma unroll
        for (int r = 0; r < 4; ++r)
            Y[(size_t)(g * 4 + r) * KGD + n] = tot[1 + r] + b_dyn[r];
    }
}

// ---------------- K3: new_feats = l2norm(Y @ W_lin^T + b_lin) ----------------
__global__ __launch_bounds__(256) void newfeat_kernel(
        const float* __restrict__ Y, const float* __restrict__ W_lin,
        const float* __restrict__ b_lin, float* __restrict__ NF) {
    __shared__ float sy[4][KGD];
    __shared__ float red[4][4];
    __shared__ float tot[4];
    int b0 = blockIdx.x * 4;
    int tid = threadIdx.x;
    for (int l = tid; l < 4 * KGD; l += 256)
        sy[l / KGD][l % KGD] = Y[(size_t)b0 * KGD + l];
    __syncthreads();

    float out[4][8];
    float ssq[4] = {0.f, 0.f, 0.f, 0.f};
#pragma unroll
    for (int q = 0; q < 8; ++q) {
        int o = tid + 256 * q;
        float a0 = 0.f, a1 = 0.f, a2 = 0.f, a3 = 0.f;
        const float4* wr = (const float4*)(W_lin + (size_t)o * KGD);
        for (int i4 = 0; i4 < KGD / 4; ++i4) {
            float4 w  = wr[i4];
            float4 s0 = *(const float4*)&sy[0][i4 * 4];
            float4 s1 = *(const float4*)&sy[1][i4 * 4];
            float4 s2 = *(const float4*)&sy[2][i4 * 4];
            float4 s3 = *(const float4*)&sy[3][i4 * 4];
            a0 += w.x * s0.x + w.y * s0.y + w.z * s0.z + w.w * s0.w;
            a1 += w.x * s1.x + w.y * s1.y + w.z * s1.z + w.w * s1.w;
            a2 += w.x * s2.x + w.y * s2.y + w.z * s2.z + w.w * s2.w;
            a3 += w.x * s3.x + w.y * s3.y + w.z * s3.z + w.w * s3.w;
        }
        float bl = b_lin[o];
        out[0][q] = a0 + bl; out[1][q] = a1 + bl;
        out[2][q] = a2 + bl; out[3][q] = a3 + bl;
#pragma unroll
        for (int r = 0; r < 4; ++r) ssq[r] += out[r][q] * out[r][q];
    }

    int lane = tid & 63, wid = tid >> 6;
#pragma unroll
    for (int c = 0; c < 4; ++c) {
        float v = ssq[c];
        for (int o = 32; o > 0; o >>= 1) v += __shfl_down(v, o, 64);
        if (lane == 0) red[c][wid] = v;
    }
    __syncthreads();
    if (tid < 4) tot[tid] = red[tid][0] + red[tid][1] + red[tid][2] + red[tid][3];
    __syncthreads();
#pragma unroll
    for (int r = 0; r < 4; ++r) {
        float norm = sqrtf(tot[r]) + 1e-8f;
#pragma unroll
        for (int q = 0; q < 8; ++q) {
            int o = tid + 256 * q;
            NF[(size_t)(b0 + r) * E_ + o] = out[r][q] / norm;
        }
    }
}

// ---------------- K4: GEMM1  h = X @ W1^T + b1  (49152x512 @ 512x1024) ----------------
__global__ __launch_bounds__(256) void gemm1_kernel(
        const float* __restrict__ X, const float* __restrict__ W1,
        const float* __restrict__ b1, float* __restrict__ Hb) {
    __shared__ float As[16][132];   // [k][m], 128 rows used
    __shared__ float Bs[16][68];    // [k][n], 64 cols used
    int n0 = blockIdx.x * 64;
    int m0 = blockIdx.y * 128;
    int tid = threadIdx.x;
    int tx = tid & 15, ty = tid >> 4;
    float acc[8][4];
#pragma unroll
    for (int i = 0; i < 8; ++i)
#pragma unroll
        for (int j = 0; j < 4; ++j) acc[i][j] = 0.f;

    for (int k0 = 0; k0 < D_; k0 += 16) {
#pragma unroll
        for (int l0 = 0; l0 < 512; l0 += 256) {
            int l = l0 + tid;
            int row = l >> 2, k4 = (l & 3) << 2;
            float4 v = *(const float4*)&X[(size_t)(m0 + row) * D_ + k0 + k4];
            As[k4 + 0][row] = v.x; As[k4 + 1][row] = v.y;
            As[k4 + 2][row] = v.z; As[k4 + 3][row] = v.w;
        }
        {
            int row = tid >> 2, k4 = (tid & 3) << 2;
            float4 v = *(const float4*)&W1[(size_t)(n0 + row) * D_ + k0 + k4];
            Bs[k4 + 0][row] = v.x; Bs[k4 + 1][row] = v.y;
            Bs[k4 + 2][row] = v.z; Bs[k4 + 3][row] = v.w;
        }
        __syncthreads();
#pragma unroll
        for (int k = 0; k < 16; ++k) {
            float4 a0 = *(const float4*)&As[k][ty * 8];
            float4 a1 = *(const float4*)&As[k][ty * 8 + 4];
            float4 bb = *(const float4*)&Bs[k][tx * 4];
            float av[8] = {a0.x, a0.y, a0.z, a0.w, a1.x, a1.y, a1.z, a1.w};
            float bv[4] = {bb.x, bb.y, bb.z, bb.w};
#pragma unroll
            for (int i = 0; i < 8; ++i)
#pragma unroll
                for (int j = 0; j < 4; ++j) acc[i][j] += av[i] * bv[j];
        }
        __syncthreads();
    }
#pragma unroll
    for (int i = 0; i < 8; ++i) {
        int m = m0 + ty * 8 + i;
        int c = n0 + tx * 4;
        float4 o;
        o.x = acc[i][0] + b1[c + 0];
        o.y = acc[i][1] + b1[c + 1];
        o.z = acc[i][2] + b1[c + 2];
        o.w = acc[i][3] + b1[c + 3];
        *(float4*)&Hb[(size_t)m * H_ + c] = o;
    }
}

// ---------------- K5: BN column stats (fp64 atomics) ----------------
__global__ __launch_bounds__(256) void stats_kernel(
        const float* __restrict__ Hb, double* __restrict__ stats) {
    int blk = blockIdx.x;     // 0..511, strip of 96 rows
    int tid = threadIdx.x;
    double s[4] = {0, 0, 0, 0}, q[4] = {0, 0, 0, 0};
    for (int r = 0; r < 96; ++r) {
        size_t base = (size_t)(blk * 96 + r) * H_;
#pragma unroll
        for (int c = 0; c < 4; ++c) {
            float v = Hb[base + tid + c * 256];
            s[c] += v;
            q[c] += (double)v * (double)v;
        }
    }
#pragma unroll
    for (int c = 0; c < 4; ++c) {
        atomicAdd(&stats[tid + c * 256], s[c]);
        atomicAdd(&stats[H_ + tid + c * 256], q[c]);
    }
}

// ---------------- K6: finalize BN -> scale/shift ----------------
__global__ void finalize_kernel(const double* __restrict__ stats,
                                const float* __restrict__ gamma,
                                const float* __restrict__ beta,
                                float* __restrict__ scsh) {
    int c = blockIdx.x * 256 + threadIdx.x;
    if (c >= H_) return;
    double mean = stats[c] / (double)M1;
    double var  = stats[H_ + c] / (double)M1 - mean * mean;
    float sc = gamma[c] * (float)(1.0 / sqrt(var + 1e-5));
    float sh = beta[c] - (float)mean * sc;
    scsh[c] = sc;
    scsh[H_ + c] = sh;
}

// ---------------- K7: GEMM2 + BN-apply + ReLU + maxpool + bias + residual ----------------
__global__ __launch_bounds__(256) void gemm2_kernel(
        const float* __restrict__ Hb, const float* __restrict__ W2,
        const float* __restrict__ b2, const float* __restrict__ scsh,
        const float* __restrict__ NF, float* __restrict__ out) {
    __shared__ float As[16][100];   // [k][row<96]
    __shared__ float Bs[16][132];   // [k][n<128]
    __shared__ float sSc[H_];
    __shared__ float sSh[H_];
    int n0 = blockIdx.x * 128;
    int b  = blockIdx.y;
    int tid = threadIdx.x;
    int tx = tid & 15, ty = tid >> 4;
    for (int l = tid; l < H_; l += 256) { sSc[l] = scsh[l]; sSh[l] = scsh[H_ + l]; }
    float acc[6][8];
#pragma unroll
    for (int i = 0; i < 6; ++i)
#pragma unroll
        for (int j = 0; j < 8; ++j) acc[i][j] = 0.f;
    __syncthreads();

    for (int k0 = 0; k0 < H_; k0 += 16) {
        for (int l = tid; l < 384; l += 256) {
            int row = l >> 2, k4 = (l & 3) << 2;
            float4 v = *(const float4*)&Hb[(size_t)(b * 96 + row) * H_ + k0 + k4];
            As[k4 + 0][row] = fmaxf(0.f, v.x * sSc[k0 + k4 + 0] + sSh[k0 + k4 + 0]);
            As[k4 + 1][row] = fmaxf(0.f, v.y * sSc[k0 + k4 + 1] + sSh[k0 + k4 + 1]);
            As[k4 + 2][row] = fmaxf(0.f, v.z * sSc[k0 + k4 + 2] + sSh[k0 + k4 + 2]);
            As[k4 + 3][row] = fmaxf(0.f, v.w * sSc[k0 + k4 + 3] + sSh[k0 + k4 + 3]);
        }
#pragma unroll
        for (int l0 = 0; l0 < 512; l0 += 256) {
            int l = l0 + tid;
            int row = l >> 2, k4 = (l & 3) << 2;
            float4 v = *(const float4*)&W2[(size_t)(n0 + row) * H_ + k0 + k4];
            Bs[k4 + 0][row] = v.x; Bs[k4 + 1][row] = v.y;
            Bs[k4 + 2][row] = v.z; Bs[k4 + 3][row] = v.w;
        }
        __syncthreads();
#pragma unroll
        for (int k = 0; k < 16; ++k) {
            float2 a01 = *(const float2*)&As[k][ty * 6];
            float2 a23 = *(const float2*)&As[k][ty * 6 + 2];
            float2 a45 = *(const float2*)&As[k][ty * 6 + 4];
            float4 b0  = *(const float4*)&Bs[k][tx * 8];
            float4 b1v = *(const float4*)&Bs[k][tx * 8 + 4];
            float av[6] = {a01.x, a01.y, a23.x, a23.y, a45.x, a45.y};
            float bv[8] = {b0.x, b0.y, b0.z, b0.w, b1v.x, b1v.y, b1v.z, b1v.w};
#pragma unroll
            for (int i = 0; i < 6; ++i)
#pragma unroll
                for (int j = 0; j < 8; ++j) acc[i][j] += av[i] * bv[j];
        }
        __syncthreads();
    }

    // maxpool over the 96 token rows
    float* smax = (float*)&Bs[0][0];   // 16 x 128 floats, fits in Bs
#pragma unroll
    for (int j = 0; j < 8; ++j) {
        float m = acc[0][j];
#pragma unroll
        for (int i = 1; i < 6; ++i) m = fmaxf(m, acc[i][j]);
        smax[ty * 128 + tx * 8 + j] = m;
    }
    __syncthreads();
    if (tid < 128) {
        float m = smax[tid];
#pragma unroll
        for (int w = 1; w < 16; ++w) m = fmaxf(m, smax[w * 128 + tid]);
        int c = n0 + tid;
        out[(size_t)b * E_ + c] = m + b2[c] + NF[(size_t)b * E_ + c];
    }
}

// ---------------- launch ----------------
extern "C" void kernel_launch(void* const* d_in, const int* in_sizes, int n_in,
                              void* d_out, int out_size, void* d_ws, size_t ws_size,
                              hipStream_t stream) {
    (void)in_sizes; (void)n_in; (void)out_size; (void)ws_size;
    const float* base  = (const float*)d_in[0];
    const float* atten = (const float*)d_in[1];
    // d_in[2] = pid: unused (uniform contiguous groups of 4 by construction)
    const float* W_dyn = (const float*)d_in[3];
    const float* b_dyn = (const float*)d_in[4];
    const float* W_lin = (const float*)d_in[5];
    const float* b_lin = (const float*)d_in[6];
    const float* W1    = (const float*)d_in[7];
    const float* b1    = (const float*)d_in[8];
    const float* gamma = (const float*)d_in[9];
    const float* beta  = (const float*)d_in[10];
    const float* W2    = (const float*)d_in[11];
    const float* b2    = (const float*)d_in[12];
    float* out = (float*)d_out;

    char* w = (char*)d_ws;
    int*    idx   = (int*)(w);                    // 196608 B
    float*  Y     = (float*)(w + 196608);         // 786432 B
    float*  NF    = (float*)(w + 983040);         // 4 MB
    double* stats = (double*)(w + 5177344);       // 16 KB
    float*  scsh  = (float*)(w + 5193728);        // 8 KB
    float*  X     = (float*)(w + 5201920);        // 100.7 MB
    float*  Hb    = (float*)(w + 105865216);      // 201.3 MB; total ~293 MiB

    zero_stats_kernel<<<8, 256, 0, stream>>>(stats);
    topk_kernel<<<B_, 256, 0, stream>>>(atten, idx);
    gather_kernel<<<M1, 256, 0, stream>>>(base, idx, W_dyn, b_dyn, X, Y);
    newfeat_kernel<<<B_ / 4, 256, 0, stream>>>(Y, W_lin, b_lin, NF);
    gemm1_kernel<<<dim3(H_ / 64, M1 / 128), 256, 0, stream>>>(X, W1, b1, Hb);
    stats_kernel<<<B_, 256, 0, stream>>>(Hb, stats);
    finalize_kernel<<<4, 256, 0, stream>>>(stats, gamma, beta, scsh);
    gemm2_kernel<<<dim3(E_ / 128, B_), 256, 0, stream>>>(Hb, W2, b2, scsh, NF, out);
}

// Round 2
// 843.128 us; speedup vs baseline: 4.2521x; 4.2521x over previous
//
#include <hip/hip_runtime.h>
#include <math.h>

#define B_   512
#define N_   193
#define D_   512
#define E_   2048
#define KTOK 96
#define H_   1024
#define M1   (B_ * KTOK)      // 49152
#define KGD  (KTOK * 4)       // 384

typedef _Float16 half8 __attribute__((ext_vector_type(8)));
typedef _Float16 half4v __attribute__((ext_vector_type(4)));
typedef float floatx4 __attribute__((ext_vector_type(4)));

// async global->LDS, 16B per lane; LDS dest = wave-uniform base + lane*16
__device__ __forceinline__ void gll16(const _Float16* g, _Float16* l) {
    __builtin_amdgcn_global_load_lds(
        (const __attribute__((address_space(1))) unsigned int*)(const void*)g,
        (__attribute__((address_space(3))) unsigned int*)(void*)l, 16, 0, 0);
}

// ---------------- K0: zero BN stats ----------------
__global__ void zero_stats_kernel(double* stats) {
    int i = blockIdx.x * 256 + threadIdx.x;
    if (i < 2 * H_) stats[i] = 0.0;
}

// ---------------- K1: exact stable top-k (rank count) ----------------
__global__ void topk_kernel(const float* __restrict__ atten, int* __restrict__ idx) {
    __shared__ float s[N_];
    int b = blockIdx.x;
    const float* row = atten + (size_t)b * N_ * N_;   // atten[b, 0, :]
    for (int i = threadIdx.x; i < N_; i += blockDim.x)
        s[i] = (i == 0) ? -1.0f : row[i];
    __syncthreads();
    for (int i = threadIdx.x; i < N_; i += blockDim.x) {
        float v = s[i];
        int rank = 0;
        for (int j = 0; j < N_; ++j) {
            float u = s[j];
            rank += (u > v) || (u == v && j < i);
        }
        if (rank < KTOK) idx[b * KTOK + rank] = i;
    }
}

// ---------------- K2: gather + l2norm -> Xh (f16) + dyn-proj stage 1 (Y) ----------------
__global__ __launch_bounds__(256) void gather_kernel(
        const float* __restrict__ base, const int* __restrict__ idx,
        const float* __restrict__ W_dyn, const float* __restrict__ b_dyn,
        _Float16* __restrict__ Xh, float* __restrict__ Y) {
    int rowid = blockIdx.x;                 // 0..49151 = b*96 + t
    int b = rowid / KTOK, t = rowid - b * KTOK;
    int tid = threadIdx.x;
    int tok = idx[rowid];
    const float* src = base + ((size_t)b * N_ + tok) * D_;
    float v0 = src[tid], v1 = src[tid + 256];

    float vals[5];
    vals[0] = v0 * v0 + v1 * v1;
#pragma unroll
    for (int r = 0; r < 4; ++r)
        vals[1 + r] = v0 * W_dyn[r * D_ + tid] + v1 * W_dyn[r * D_ + tid + 256];

    __shared__ float red[5][4];
    __shared__ float tot[5];
    int lane = tid & 63, wid = tid >> 6;
#pragma unroll
    for (int c = 0; c < 5; ++c) {
        float v = vals[c];
        for (int o = 32; o > 0; o >>= 1) v += __shfl_down(v, o, 64);
        if (lane == 0) red[c][wid] = v;
    }
    __syncthreads();
    if (tid < 5) tot[tid] = red[tid][0] + red[tid][1] + red[tid][2] + red[tid][3];
    __syncthreads();

    float norm = sqrtf(tot[0]) + 1e-8f;
    size_t xb = (size_t)rowid * D_;
    Xh[xb + tid]       = (_Float16)(v0 / norm);
    Xh[xb + tid + 256] = (_Float16)(v1 / norm);
    if (tid == 0) {
        int g = b >> 2;
        int n = (b & 3) * KTOK + t;
#pragma unroll
        for (int r = 0; r < 4; ++r)
            Y[(size_t)(g * 4 + r) * KGD + n] = tot[1 + r] + b_dyn[r];
    }
}

// ---------------- K3: new_feats = l2norm(Y @ W_lin^T + b_lin) (fp32, small) ----------------
__global__ __launch_bounds__(256) void newfeat_kernel(
        const float* __restrict__ Y, const float* __restrict__ W_lin,
        const float* __restrict__ b_lin, float* __restrict__ NF) {
    __shared__ float sy[4][KGD];
    __shared__ float red[4][4];
    __shared__ float tot[4];
    int b0 = blockIdx.x * 4;
    int tid = threadIdx.x;
    for (int l = tid; l < 4 * KGD; l += 256)
        sy[l / KGD][l % KGD] = Y[(size_t)b0 * KGD + l];
    __syncthreads();

    float out[4][8];
    float ssq[4] = {0.f, 0.f, 0.f, 0.f};
#pragma unroll
    for (int q = 0; q < 8; ++q) {
        int o = tid + 256 * q;
        float a0 = 0.f, a1 = 0.f, a2 = 0.f, a3 = 0.f;
        const float4* wr = (const float4*)(W_lin + (size_t)o * KGD);
        for (int i4 = 0; i4 < KGD / 4; ++i4) {
            float4 w  = wr[i4];
            float4 s0 = *(const float4*)&sy[0][i4 * 4];
            float4 s1 = *(const float4*)&sy[1][i4 * 4];
            float4 s2 = *(const float4*)&sy[2][i4 * 4];
            float4 s3 = *(const float4*)&sy[3][i4 * 4];
            a0 += w.x * s0.x + w.y * s0.y + w.z * s0.z + w.w * s0.w;
            a1 += w.x * s1.x + w.y * s1.y + w.z * s1.z + w.w * s1.w;
            a2 += w.x * s2.x + w.y * s2.y + w.z * s2.z + w.w * s2.w;
            a3 += w.x * s3.x + w.y * s3.y + w.z * s3.z + w.w * s3.w;
        }
        float bl = b_lin[o];
        out[0][q] = a0 + bl; out[1][q] = a1 + bl;
        out[2][q] = a2 + bl; out[3][q] = a3 + bl;
#pragma unroll
        for (int r = 0; r < 4; ++r) ssq[r] += out[r][q] * out[r][q];
    }

    int lane = tid & 63, wid = tid >> 6;
#pragma unroll
    for (int c = 0; c < 4; ++c) {
        float v = ssq[c];
        for (int o = 32; o > 0; o >>= 1) v += __shfl_down(v, o, 64);
        if (lane == 0) red[c][wid] = v;
    }
    __syncthreads();
    if (tid < 4) tot[tid] = red[tid][0] + red[tid][1] + red[tid][2] + red[tid][3];
    __syncthreads();
#pragma unroll
    for (int r = 0; r < 4; ++r) {
        float norm = sqrtf(tot[r]) + 1e-8f;
#pragma unroll
        for (int q = 0; q < 8; ++q) {
            int o = tid + 256 * q;
            NF[(size_t)(b0 + r) * E_ + o] = out[r][q] / norm;
        }
    }
}

// ---------------- K4: convert W1, W2 to f16 ----------------
__global__ __launch_bounds__(256) void convw_kernel(
        const float* __restrict__ W1, const float* __restrict__ W2,
        _Float16* __restrict__ W1h, _Float16* __restrict__ W2h) {
    int i = blockIdx.x * 256 + threadIdx.x;
    if (i < 131072) {                       // W1: 1024*512/4
        float4 v = *(const float4*)&W1[(size_t)i * 4];
        half4v o = {(_Float16)v.x, (_Float16)v.y, (_Float16)v.z, (_Float16)v.w};
        *(half4v*)&W1h[(size_t)i * 4] = o;
    } else {                                // W2: 2048*1024/4
        int j = i - 131072;
        float4 v = *(const float4*)&W2[(size_t)j * 4];
        half4v o = {(_Float16)v.x, (_Float16)v.y, (_Float16)v.z, (_Float16)v.w};
        *(half4v*)&W2h[(size_t)j * 4] = o;
    }
}

// ---------------- K5: GEMM1 MFMA  Hb = Xh @ W1h^T + b1  (f16 out) ----------------
// tile 128x128, BK=32, 4 waves (2x2 of 64x64). LDS fragment-order [kg][m][8].
__global__ __launch_bounds__(256) void gemm1_mfma(
        const _Float16* __restrict__ Xh, const _Float16* __restrict__ W1h,
        const float* __restrict__ b1, _Float16* __restrict__ Hbh) {
    __shared__ _Float16 Al[2][4096];
    __shared__ _Float16 Bl[2][4096];
    int tid = threadIdx.x;
    int lane = tid & 63, w = tid >> 6;
    int wr = w >> 1, wc = w & 1;
    int n0 = blockIdx.x * 128, m0 = blockIdx.y * 128;

    // staging: wave w issues insts i=w and i=w+4 for A and B.
    // inst i: kg = i>>1, m-half = (i&1)*64; per-lane m = half + lane.
    const _Float16* srcA0 = Xh  + ((size_t)(m0 + (w & 1) * 64 + lane)) * 512 + (w >> 1) * 8;
    const _Float16* srcA1 = srcA0 + 16;   // kg+2 -> +16 elems
    const _Float16* srcB0 = W1h + ((size_t)(n0 + (w & 1) * 64 + lane)) * 512 + (w >> 1) * 8;
    const _Float16* srcB1 = srcB0 + 16;
    int la0 = w * 512, la1 = (w + 4) * 512;

    floatx4 zero = {0.f, 0.f, 0.f, 0.f};
    floatx4 acc[4][4];
#pragma unroll
    for (int i = 0; i < 4; ++i)
#pragma unroll
        for (int j = 0; j < 4; ++j) acc[i][j] = zero;

    int aoff = ((lane >> 4) * 128 + wr * 64 + (lane & 15)) * 8;
    int boff = ((lane >> 4) * 128 + wc * 64 + (lane & 15)) * 8;

#define G1_STAGE(buf, kt) { int ko = (kt) * 32;            \
    gll16(srcA0 + ko, &Al[buf][la0]);                      \
    gll16(srcA1 + ko, &Al[buf][la1]);                      \
    gll16(srcB0 + ko, &Bl[buf][la0]);                      \
    gll16(srcB1 + ko, &Bl[buf][la1]); }

    G1_STAGE(0, 0);
    __syncthreads();
    int cur = 0;
    for (int kt = 0; kt < 16; ++kt) {
        if (kt < 15) G1_STAGE(cur ^ 1, kt + 1);
        half8 a[4], bfr[4];
#pragma unroll
        for (int f = 0; f < 4; ++f) {
            a[f]   = *(const half8*)&Al[cur][aoff + f * 128];
            bfr[f] = *(const half8*)&Bl[cur][boff + f * 128];
        }
#pragma unroll
        for (int i = 0; i < 4; ++i)
#pragma unroll
            for (int j = 0; j < 4; ++j)
                acc[i][j] = __builtin_amdgcn_mfma_f32_16x16x32_f16(a[i], bfr[j], acc[i][j], 0, 0, 0);
        __syncthreads();
        cur ^= 1;
    }

    // epilogue: C/D layout col = lane&15, row = (lane>>4)*4 + r
#pragma unroll
    for (int i = 0; i < 4; ++i) {
        int row = m0 + wr * 64 + i * 16 + (lane >> 4) * 4;
#pragma unroll
        for (int j = 0; j < 4; ++j) {
            int col = n0 + wc * 64 + j * 16 + (lane & 15);
            float bb = b1[col];
#pragma unroll
            for (int r = 0; r < 4; ++r)
                Hbh[(size_t)(row + r) * H_ + col] = (_Float16)(acc[i][j][r] + bb);
        }
    }
}

// ---------------- K6: BN column stats from f16 Hb ----------------
__global__ __launch_bounds__(256) void stats_kernel(
        const _Float16* __restrict__ Hbh, double* __restrict__ stats) {
    int blk = blockIdx.x, tid = threadIdx.x;
    int c0 = tid * 4;
    double s[4] = {0, 0, 0, 0}, q[4] = {0, 0, 0, 0};
    for (int r = 0; r < 96; ++r) {
        const half4v v = *(const half4v*)&Hbh[(size_t)(blk * 96 + r) * H_ + c0];
#pragma unroll
        for (int c = 0; c < 4; ++c) {
            float f = (float)v[c];
            s[c] += f;
            q[c] += (double)f * (double)f;
        }
    }
#pragma unroll
    for (int c = 0; c < 4; ++c) {
        atomicAdd(&stats[c0 + c], s[c]);
        atomicAdd(&stats[H_ + c0 + c], q[c]);
    }
}

// ---------------- K7: finalize BN -> scale/shift ----------------
__global__ void finalize_kernel(const double* __restrict__ stats,
                                const float* __restrict__ gamma,
                                const float* __restrict__ beta,
                                float* __restrict__ scsh) {
    int c = blockIdx.x * 256 + threadIdx.x;
    if (c >= H_) return;
    double mean = stats[c] / (double)M1;
    double var  = stats[H_ + c] / (double)M1 - mean * mean;
    float sc = gamma[c] * (float)(1.0 / sqrt(var + 1e-5));
    float sh = beta[c] - (float)mean * sc;
    scsh[c] = sc;
    scsh[H_ + c] = sh;
}

// ---------------- K8: BN-apply + ReLU -> A2h (f16) ----------------
__global__ __launch_bounds__(256) void bnrelu_kernel(
        const _Float16* __restrict__ Hbh, const float* __restrict__ scsh,
        _Float16* __restrict__ A2h) {
    size_t i = (size_t)blockIdx.x * 256 + threadIdx.x;
    size_t e0 = i * 8;
    int col0 = (int)(e0 & (H_ - 1));
    half8 v = *(const half8*)&Hbh[e0];
    float4 sc0 = *(const float4*)&scsh[col0];
    float4 sc1 = *(const float4*)&scsh[col0 + 4];
    float4 sh0 = *(const float4*)&scsh[H_ + col0];
    float4 sh1 = *(const float4*)&scsh[H_ + col0 + 4];
    half8 o;
    o[0] = (_Float16)fmaxf(0.f, (float)v[0] * sc0.x + sh0.x);
    o[1] = (_Float16)fmaxf(0.f, (float)v[1] * sc0.y + sh0.y);
    o[2] = (_Float16)fmaxf(0.f, (float)v[2] * sc0.z + sh0.z);
    o[3] = (_Float16)fmaxf(0.f, (float)v[3] * sc0.w + sh0.w);
    o[4] = (_Float16)fmaxf(0.f, (float)v[4] * sc1.x + sh1.x);
    o[5] = (_Float16)fmaxf(0.f, (float)v[5] * sc1.y + sh1.y);
    o[6] = (_Float16)fmaxf(0.f, (float)v[6] * sc1.z + sh1.z);
    o[7] = (_Float16)fmaxf(0.f, (float)v[7] * sc1.w + sh1.w);
    *(half8*)&A2h[e0] = o;
}

// ---------------- K9: GEMM2 MFMA + fused maxpool + b2 + NF ----------------
// one batch (96 rows) x 256 cols per block; 4 waves, wave w -> cols w*64.
__global__ __launch_bounds__(256) void gemm2_mfma(
        const _Float16* __restrict__ A2h, const _Float16* __restrict__ W2h,
        const float* __restrict__ b2, const float* __restrict__ NF,
        float* __restrict__ out) {
    __shared__ _Float16 Al[2][3072];       // [kg][m<96][8]
    __shared__ _Float16 Bl[2][8192];       // [kg][n<256][8]
    int tid = threadIdx.x;
    int lane = tid & 63, w = tid >> 6;
    int b = blockIdx.x, n0 = blockIdx.y * 256;

    // A staging: 6 insts, wave w<3 issues i=w*2, w*2+1; chunk c=i*64+lane -> kg=c/96, m=c%96
    int cA0 = w * 128 + lane, cA1 = cA0 + 64;
    int kgA0 = cA0 / 96, mA0 = cA0 - kgA0 * 96;
    int kgA1 = cA1 / 96, mA1 = cA1 - kgA1 * 96;
    const _Float16* srcA0 = A2h + ((size_t)(b * 96 + mA0)) * H_ + kgA0 * 8;
    const _Float16* srcA1 = A2h + ((size_t)(b * 96 + mA1)) * H_ + kgA1 * 8;
    int laA0 = w * 1024, laA1 = w * 1024 + 512;
    // B staging: 16 insts, wave w issues i=w*4+q: kg=w, n=q*64+lane
    const _Float16* srcB = W2h + ((size_t)(n0 + lane)) * H_ + w * 8;
    int lbB = w * 2048;                    // (w*4)*512

    floatx4 zero = {0.f, 0.f, 0.f, 0.f};
    floatx4 acc[6][4];
#pragma unroll
    for (int i = 0; i < 6; ++i)
#pragma unroll
        for (int j = 0; j < 4; ++j) acc[i][j] = zero;

    int aoff = ((lane >> 4) * 96  + (lane & 15)) * 8;
    int boff = ((lane >> 4) * 256 + w * 64 + (lane & 15)) * 8;

#define G2_STAGE(buf, kt) { int ko = (kt) * 32;                      \
    if (w < 3) {                                                     \
        gll16(srcA0 + ko, &Al[buf][laA0]);                           \
        gll16(srcA1 + ko, &Al[buf][laA1]);                           \
    }                                                                \
    gll16(srcB + ko,               &Bl[buf][lbB]);                   \
    gll16(srcB + 64 * 1024 + ko,   &Bl[buf][lbB + 512]);             \
    gll16(srcB + 128 * 1024 + ko,  &Bl[buf][lbB + 1024]);            \
    gll16(srcB + 192 * 1024 + ko,  &Bl[buf][lbB + 1536]); }

    G2_STAGE(0, 0);
    __syncthreads();
    int cur = 0;
    for (int kt = 0; kt < 32; ++kt) {
        if (kt < 31) G2_STAGE(cur ^ 1, kt + 1);
        half8 a[6], bfr[4];
#pragma unroll
        for (int f = 0; f < 6; ++f) a[f] = *(const half8*)&Al[cur][aoff + f * 128];
#pragma unroll
        for (int f = 0; f < 4; ++f) bfr[f] = *(const half8*)&Bl[cur][boff + f * 128];
#pragma unroll
        for (int i = 0; i < 6; ++i)
#pragma unroll
            for (int j = 0; j < 4; ++j)
                acc[i][j] = __builtin_amdgcn_mfma_f32_16x16x32_f16(a[i], bfr[j], acc[i][j], 0, 0, 0);
        __syncthreads();
        cur ^= 1;
    }

    // fused maxpool over 96 rows + b2 + NF
#pragma unroll
    for (int j = 0; j < 4; ++j) {
        float m = -3.4e38f;
#pragma unroll
        for (int i = 0; i < 6; ++i)
#pragma unroll
            for (int r = 0; r < 4; ++r) m = fmaxf(m, acc[i][j][r]);
        m = fmaxf(m, __shfl_xor(m, 16));
        m = fmaxf(m, __shfl_xor(m, 32));
        if (lane < 16) {
            int col = n0 + w * 64 + j * 16 + lane;
            out[(size_t)b * E_ + col] = m + b2[col] + NF[(size_t)b * E_ + col];
        }
    }
}

// ---------------- launch ----------------
extern "C" void kernel_launch(void* const* d_in, const int* in_sizes, int n_in,
                              void* d_out, int out_size, void* d_ws, size_t ws_size,
                              hipStream_t stream) {
    (void)in_sizes; (void)n_in; (void)out_size; (void)ws_size;
    const float* base  = (const float*)d_in[0];
    const float* atten = (const float*)d_in[1];
    // d_in[2] = pid: unused (uniform contiguous groups of 4 by construction)
    const float* W_dyn = (const float*)d_in[3];
    const float* b_dyn = (const float*)d_in[4];
    const float* W_lin = (const float*)d_in[5];
    const float* b_lin = (const float*)d_in[6];
    const float* W1    = (const float*)d_in[7];
    const float* b1    = (const float*)d_in[8];
    const float* gamma = (const float*)d_in[9];
    const float* beta  = (const float*)d_in[10];
    const float* W2    = (const float*)d_in[11];
    const float* b2    = (const float*)d_in[12];
    float* out = (float*)d_out;

    char* wsp = (char*)d_ws;
    int*      idx   = (int*)(wsp);                       // 196608 B
    float*    Y     = (float*)(wsp + 196608);            // 786432 B
    float*    NF    = (float*)(wsp + 983040);            // 4 MB
    double*   stats = (double*)(wsp + 5177344);          // 16 KB
    float*    scsh  = (float*)(wsp + 5193728);           // 8 KB
    _Float16* W1h   = (_Float16*)(wsp + 5201920);        // 1 MB
    _Float16* W2h   = (_Float16*)(wsp + 6250496);        // 4 MB
    _Float16* Xh    = (_Float16*)(wsp + 10444800);       // 50.3 MB
    _Float16* Hbh   = (_Float16*)(wsp + 60776448);       // 100.7 MB
    _Float16* A2h   = (_Float16*)(wsp + 161439744);      // 100.7 MB; total ~250 MiB

    zero_stats_kernel<<<8, 256, 0, stream>>>(stats);
    topk_kernel<<<B_, 256, 0, stream>>>(atten, idx);
    convw_kernel<<<2560, 256, 0, stream>>>(W1, W2, W1h, W2h);
    gather_kernel<<<M1, 256, 0, stream>>>(base, idx, W_dyn, b_dyn, Xh, Y);
    newfeat_kernel<<<B_ / 4, 256, 0, stream>>>(Y, W_lin, b_lin, NF);
    gemm1_mfma<<<dim3(H_ / 128, M1 / 128), 256, 0, stream>>>(Xh, W1h, b1, Hbh);
    stats_kernel<<<B_, 256, 0, stream>>>(Hbh, stats);
    finalize_kernel<<<4, 256, 0, stream>>>(stats, gamma, beta, scsh);
    bnrelu_kernel<<<(M1 * H_ / 8) / 256, 256, 0, stream>>>(Hbh, scsh, A2h);
    gemm2_mfma<<<dim3(B_, E_ / 256), 256, 0, stream>>>(A2h, W2h, b2, NF, out);
}